// Round 3
// baseline (539.375 us; speedup 1.0000x reference)
//
#include <hip/hip_runtime.h>
#include <hip/hip_bf16.h>
#include <stdint.h>
#include <stddef.h>

// LiteratiQuantLinear: out = x @ (sign(w)*clamp(scales,1e-8))^T
// M=8192 (4x2048), N=4096 (O), K=4096 (C), group=128 along K.
//
// R5: R4 measured cyc/tile/CU = 2316 = MFMA(1242)+LDS(1152) serialized:
// 8 barrier-locked waves all dump 96 ds_read_b128 at tile top while the MFMA
// pipe idles. This round attacks the LDS term:
//   - 4 waves (256 thr), wave tile 128x128 (8x8 16x16 frags, acc=256 VGPR):
//     reads/MFMA 0.375 -> 0.25; per-CU LDS time/tile 1152 -> 768 cyc
//   - read order (av01,bv01,...) matched to blocked 2x2 MFMA order: first
//     cluster needs 4 reads -> ~200 cyc exposed head, rest hides under MFMA
//   - 1 wave/SIMD (launch_bounds(256,1)); ~360 VGPR < 450 no-spill line
//   - 4-buffer ring, prefetch depth 3, counted vmcnt(16) (8 DMA/tile/wave),
//     XOR-swizzled reads w/ inverse swizzle on DMA global src (bank-conflict
//     0, verified R3/R4) -- all unchanged
// Prep kernel unchanged from R2.

#define M_DIM 8192
#define N_DIM 4096
#define K_DIM 4096
#define BM 256
#define BN 256
#define BK 32
#define NT (K_DIM / BK)  // 128 K-tiles

typedef __bf16 bf16x8 __attribute__((ext_vector_type(8)));
typedef float f32x4 __attribute__((ext_vector_type(4)));

__device__ __forceinline__ void async_copy16(const void* g, void* l) {
  __builtin_amdgcn_global_load_lds((__attribute__((address_space(1))) void*)g,
                                   (__attribute__((address_space(3))) void*)l,
                                   16, 0, 0);
}

// ---- fused prep: cast x -> bf16 AND w -> sign(w)*max(scale,1e-8) bf16 ----
#define X_THREADS ((size_t)M_DIM * K_DIM / 16)  // 2M
#define W_THREADS ((size_t)N_DIM * K_DIM / 16)  // 1M
__global__ __launch_bounds__(256) void prep_kernel(
    const float* __restrict__ x, const float* __restrict__ w,
    const float* __restrict__ scales, __bf16* __restrict__ xb,
    __bf16* __restrict__ wb) {
  const size_t t = (size_t)blockIdx.x * blockDim.x + threadIdx.x;
  if (t < X_THREADS) {
    const float4* src = (const float4*)x + t * 4;
    bf16x8* dst = (bf16x8*)xb + t * 2;
#pragma unroll
    for (int h = 0; h < 2; ++h) {
      const float4 v0 = src[h * 2 + 0];
      const float4 v1 = src[h * 2 + 1];
      bf16x8 o;
      o[0] = (__bf16)v0.x; o[1] = (__bf16)v0.y;
      o[2] = (__bf16)v0.z; o[3] = (__bf16)v0.w;
      o[4] = (__bf16)v1.x; o[5] = (__bf16)v1.y;
      o[6] = (__bf16)v1.z; o[7] = (__bf16)v1.w;
      dst[h] = o;
    }
  } else {
    const size_t u = t - X_THREADS;            // 0 .. W_THREADS-1
    const size_t idx = u * 16;                 // flat (O,C) element index
    const int o_ = (int)(idx >> 12);           // / 4096
    const int grp = (int)(idx & 4095) >> 7;    // group of 128 (16 | 128)
    const float s = fmaxf(scales[(o_ << 5) + grp], 1e-8f);
    const float4* src = (const float4*)w + u * 4;
    bf16x8* dst = (bf16x8*)wb + u * 2;
#pragma unroll
    for (int h = 0; h < 2; ++h) {
      const float4 v0 = src[h * 2 + 0];
      const float4 v1 = src[h * 2 + 1];
      bf16x8 q;
      q[0] = (__bf16)((v0.x >= 0.f) ? s : -s);
      q[1] = (__bf16)((v0.y >= 0.f) ? s : -s);
      q[2] = (__bf16)((v0.z >= 0.f) ? s : -s);
      q[3] = (__bf16)((v0.w >= 0.f) ? s : -s);
      q[4] = (__bf16)((v1.x >= 0.f) ? s : -s);
      q[5] = (__bf16)((v1.y >= 0.f) ? s : -s);
      q[6] = (__bf16)((v1.z >= 0.f) ? s : -s);
      q[7] = (__bf16)((v1.w >= 0.f) ? s : -s);
      dst[h] = q;
    }
  }
}

// ---- GEMM ----
// LDS per buffer: A 256x32 bf16 (16 KiB) + B 256x32 bf16 (16 KiB), 4 buffers
// (128 KiB ring). Slot layout (slot = 16 B = 8 bf16 of k-chunk kc):
//   slot(r, kc) = r*4 + (kc ^ ((r>>1)&3))   (SQ_LDS_BANK_CONFLICT == 0)
// Staging: 4 waves x 8 DMA; wave w stages A slabs 4w..4w+3 and B slabs
// 4w..4w+3 (slab = 16 rows). Lane l -> row-in-slab l>>2, pre-swizzled global
// k-chunk kc = (l&3)^((l>>3)&3); LDS dest linear (uniform base + lane*16).
// Pipeline: compute tile t from buf[t&3]; stage tile t+3; vmcnt(16) at tile
// end (8 insts/tile, tiles t+2,t+3 stay in flight). Tail 16 -> 8 -> 0.

#define LDS_A(b) ((char*)lds + (b) * 32768)
#define LDS_B(b) ((char*)lds + (b) * 32768 + 16384)

#define STAGE_A_TO(b) do {                        \
    char* _d = LDS_A(b);                          \
    async_copy16(aP0, _d + dA0);                  \
    async_copy16(aP1, _d + dA1);                  \
    async_copy16(aP2, _d + dA2);                  \
    async_copy16(aP3, _d + dA3);                  \
  } while (0)

#define STAGE_B_TO(b) do {                        \
    char* _d = LDS_B(b);                          \
    async_copy16(bP0, _d + dA0);                  \
    async_copy16(bP1, _d + dA1);                  \
    async_copy16(bP2, _d + dA2);                  \
    async_copy16(bP3, _d + dA3);                  \
  } while (0)

#define ADVANCE do {                              \
    aP0 += BK; aP1 += BK; aP2 += BK; aP3 += BK;   \
    bP0 += BK; bP1 += BK; bP2 += BK; bP3 += BK;   \
  } while (0)

// BUF is compile-time 0..3. Read order matches blocked 2x2 MFMA order so the
// first cluster needs only av[0],av[1],bv[0],bv[1]; compiler places counted
// lgkmcnt per consuming MFMA (verified R4 behavior).
#define TILE_BODY(BUF, DO_STAGE, VMSTR) do {                                   \
    char* _bufA = LDS_A(BUF);                                                  \
    char* _bufB = LDS_B(BUF);                                                  \
    bf16x8 _av[8], _bv[8];                                                     \
    _av[0] = *(const bf16x8*)(_bufA + aOff[0]);                                \
    _av[1] = *(const bf16x8*)(_bufA + aOff[1]);                                \
    _bv[0] = *(const bf16x8*)(_bufB + bOff[0]);                                \
    _bv[1] = *(const bf16x8*)(_bufB + bOff[1]);                                \
    if (DO_STAGE) { STAGE_A_TO((BUF + 3) & 3); STAGE_B_TO((BUF + 3) & 3); }    \
    _Pragma("unroll") for (int _j = 2; _j < 8; ++_j)                           \
      _bv[_j] = *(const bf16x8*)(_bufB + bOff[_j]);                            \
    _Pragma("unroll") for (int _i = 2; _i < 8; ++_i)                           \
      _av[_i] = *(const bf16x8*)(_bufA + aOff[_i]);                            \
    if (DO_STAGE) ADVANCE;                                                     \
    _Pragma("unroll") for (int _ip = 0; _ip < 4; ++_ip)                        \
      _Pragma("unroll") for (int _jp = 0; _jp < 4; ++_jp)                      \
        _Pragma("unroll") for (int _di = 0; _di < 2; ++_di)                    \
          _Pragma("unroll") for (int _dj = 0; _dj < 2; ++_dj)                  \
            acc[_ip * 2 + _di][_jp * 2 + _dj] =                                \
                __builtin_amdgcn_mfma_f32_16x16x32_bf16(                       \
                    _av[_ip * 2 + _di], _bv[_jp * 2 + _dj],                    \
                    acc[_ip * 2 + _di][_jp * 2 + _dj], 0, 0, 0);               \
    asm volatile("s_waitcnt " VMSTR ::: "memory");                             \
    __builtin_amdgcn_s_barrier();                                              \
    __builtin_amdgcn_sched_barrier(0); /* tile boundary: no read hoisting */   \
  } while (0)

__global__ __launch_bounds__(256, 1) void literati_gemm(
    const __bf16* __restrict__ Ab, const __bf16* __restrict__ Bb,
    float* __restrict__ C) {
  __shared__ __align__(16) char lds[4 * 32768];  // 128 KiB ring

  const int tid = threadIdx.x;
  const int lane = tid & 63;
  const int wave = tid >> 6;       // 0..3
  const int bn0 = blockIdx.x * BN;
  const int bm0 = blockIdx.y * BM;
  const int wm = wave >> 1;        // 0..1: 128-row half
  const int wn = wave & 1;         // 0..1: 128-col half

  // ---- staging decomposition: wave w -> slabs 4w..4w+3 (A and B) ----
  const int r_in = lane >> 2;                        // 0..15 row within slab
  const int kc_st = (lane & 3) ^ ((lane >> 3) & 3);  // pre-swizzled k-chunk
  const int s0 = wave * 4;
  const __bf16* aP0 = Ab + (size_t)(bm0 + (s0 + 0) * 16 + r_in) * K_DIM + kc_st * 8;
  const __bf16* aP1 = Ab + (size_t)(bm0 + (s0 + 1) * 16 + r_in) * K_DIM + kc_st * 8;
  const __bf16* aP2 = Ab + (size_t)(bm0 + (s0 + 2) * 16 + r_in) * K_DIM + kc_st * 8;
  const __bf16* aP3 = Ab + (size_t)(bm0 + (s0 + 3) * 16 + r_in) * K_DIM + kc_st * 8;
  const __bf16* bP0 = Bb + (size_t)(bn0 + (s0 + 0) * 16 + r_in) * K_DIM + kc_st * 8;
  const __bf16* bP1 = Bb + (size_t)(bn0 + (s0 + 1) * 16 + r_in) * K_DIM + kc_st * 8;
  const __bf16* bP2 = Bb + (size_t)(bn0 + (s0 + 2) * 16 + r_in) * K_DIM + kc_st * 8;
  const __bf16* bP3 = Bb + (size_t)(bn0 + (s0 + 3) * 16 + r_in) * K_DIM + kc_st * 8;
  const int dA0 = ((s0 + 0) * 64 + lane) * 16;  // linear LDS byte offsets
  const int dA1 = ((s0 + 1) * 64 + lane) * 16;
  const int dA2 = ((s0 + 2) * 64 + lane) * 16;
  const int dA3 = ((s0 + 3) * 64 + lane) * 16;

  // ---- fragment LDS byte offsets (16x16x32: row = lane&15, kc = lane>>4) ----
  const int fr = lane & 15;
  const int kc_rd = lane >> 4;  // 0..3
  int aOff[8], bOff[8];
#pragma unroll
  for (int i = 0; i < 8; ++i) {
    const int rowa = wm * 128 + i * 16 + fr;
    aOff[i] = (rowa * 4 + (kc_rd ^ ((rowa >> 1) & 3))) * 16;
    const int rowb = wn * 128 + i * 16 + fr;
    bOff[i] = (rowb * 4 + (kc_rd ^ ((rowb >> 1) & 3))) * 16;
  }

  f32x4 acc[8][8];
#pragma unroll
  for (int i = 0; i < 8; ++i)
#pragma unroll
    for (int j = 0; j < 8; ++j)
#pragma unroll
      for (int r = 0; r < 4; ++r) acc[i][j][r] = 0.f;

  // ---- prologue: stage tiles 0,1,2 (24 insts/wave), wait tile 0 ----
  STAGE_A_TO(0); STAGE_B_TO(0); ADVANCE;
  STAGE_A_TO(1); STAGE_B_TO(1); ADVANCE;
  STAGE_A_TO(2); STAGE_B_TO(2); ADVANCE;
  asm volatile("s_waitcnt vmcnt(16)" ::: "memory");
  __builtin_amdgcn_s_barrier();
  __builtin_amdgcn_sched_barrier(0);

  // ---- main loop: 31*4 = 124 tiles, ring index compile-time ----
  for (int tq = 0; tq < 31; ++tq) {
    TILE_BODY(0, 1, "vmcnt(16)");
    TILE_BODY(1, 1, "vmcnt(16)");
    TILE_BODY(2, 1, "vmcnt(16)");
    TILE_BODY(3, 1, "vmcnt(16)");
  }
  // tile 124 stages tile 127; then drain 125/126/127 (16 -> 8 -> 0 insts)
  TILE_BODY(0, 1, "vmcnt(16)");
  TILE_BODY(1, 0, "vmcnt(8)");
  TILE_BODY(2, 0, "vmcnt(0)");
  TILE_BODY(3, 0, "vmcnt(0)");

  // ---- epilogue: D layout col = lane&15, row = (lane>>4)*4 + reg ----
  const int col0 = bn0 + wn * 128 + fr;
  const int rb = bm0 + wm * 128 + (lane >> 4) * 4;
#pragma unroll
  for (int i = 0; i < 8; ++i) {
    const int row0 = rb + i * 16;
#pragma unroll
    for (int j = 0; j < 8; ++j) {
      float* p = C + (size_t)row0 * N_DIM + col0 + j * 16;
#pragma unroll
      for (int r = 0; r < 4; ++r)
        p[(size_t)r * N_DIM] = acc[i][j][r];
    }
  }
}

extern "C" void kernel_launch(void* const* d_in, const int* in_sizes, int n_in,
                              void* d_out, int out_size, void* d_ws, size_t ws_size,
                              hipStream_t stream) {
  (void)in_sizes; (void)n_in; (void)out_size; (void)ws_size;
  const float* x = (const float*)d_in[0];      // (4,2048,4096) fp32
  const float* w = (const float*)d_in[1];      // (4096,4096) fp32
  const float* sc = (const float*)d_in[2];     // (4096,32) fp32
  float* out = (float*)d_out;                  // (4,2048,4096) fp32

  __bf16* xb = (__bf16*)d_ws;
  __bf16* wb = xb + (size_t)M_DIM * K_DIM;

  const size_t total_threads = X_THREADS + W_THREADS;  // 3M
  prep_kernel<<<(int)(total_threads / 256), 256, 0, stream>>>(x, w, sc, xb, wb);

  dim3 grid(N_DIM / BN, M_DIM / BM);  // (16, 32)
  literati_gemm<<<grid, 256, 0, stream>>>(xb, wb, out);
}

// Round 4
// 481.504 us; speedup vs baseline: 1.1202x; 1.1202x over previous
//
#include <hip/hip_runtime.h>
#include <hip/hip_bf16.h>
#include <stdint.h>
#include <stddef.h>

// LiteratiQuantLinear: out = x @ (sign(w)*clamp(scales,1e-8))^T
// M=8192 (4x2048), N=4096 (O), K=4096 (C), group=128 along K.
//
// R6: R5 (128x128/wave) died of register pressure (1 wave/SIMD, 11% occ).
// Back to 8 waves / 128x64 per wave. The R3/R4 wall (cyc/tile = 2316 =
// MFMA 1242 + LDS 1152 serialized) is attacked by FRAGMENT SOFTWARE
// PIPELINING: two frag sets F0/F1 ping-pong at k-step (K=16) granularity --
// each MFMA cluster consumes registers read during the PREVIOUS step, so
// ds_reads have no consumer for ~1 step and the LDS pipe overlaps the MFMA
// pipe by construction (no lgkmcnt on the critical path). Also switched to
// 32x32x16 MFMA (R2-verified layout): 128 MFMA/CU/tile x 8.07cy = 1033 cyc
// vs 1242 for 16x16x32.
//   - staging: R4's verified scheme (linear LDS dest, pre-swizzled global
//     source, swizzled reads; SQ_LDS_BANK_CONFLICT == 0), 4 DMA/wave/tile
//   - 4-buffer ring, prefetch depth 3, steady vmcnt(4): guarantees DMA(t+1)
//     complete when tile t starts (its step-1 reads touch buf[t+1])
//   - acc 128 regs -> AGPRs; frags 2x6x4 = 48 VGPR; ~215 total < 256 ->
//     2 waves/SIMD holds
// Prep kernel unchanged from R2.

#define M_DIM 8192
#define N_DIM 4096
#define K_DIM 4096
#define BM 256
#define BN 256
#define BK 32
#define NT (K_DIM / BK)  // 128 K-tiles

typedef __bf16 bf16x8 __attribute__((ext_vector_type(8)));
typedef float f32x16 __attribute__((ext_vector_type(16)));

__device__ __forceinline__ void async_copy16(const void* g, void* l) {
  __builtin_amdgcn_global_load_lds((__attribute__((address_space(1))) void*)g,
                                   (__attribute__((address_space(3))) void*)l,
                                   16, 0, 0);
}

// ---- fused prep: cast x -> bf16 AND w -> sign(w)*max(scale,1e-8) bf16 ----
#define X_THREADS ((size_t)M_DIM * K_DIM / 16)  // 2M
#define W_THREADS ((size_t)N_DIM * K_DIM / 16)  // 1M
__global__ __launch_bounds__(256) void prep_kernel(
    const float* __restrict__ x, const float* __restrict__ w,
    const float* __restrict__ scales, __bf16* __restrict__ xb,
    __bf16* __restrict__ wb) {
  const size_t t = (size_t)blockIdx.x * blockDim.x + threadIdx.x;
  if (t < X_THREADS) {
    const float4* src = (const float4*)x + t * 4;
    bf16x8* dst = (bf16x8*)xb + t * 2;
#pragma unroll
    for (int h = 0; h < 2; ++h) {
      const float4 v0 = src[h * 2 + 0];
      const float4 v1 = src[h * 2 + 1];
      bf16x8 o;
      o[0] = (__bf16)v0.x; o[1] = (__bf16)v0.y;
      o[2] = (__bf16)v0.z; o[3] = (__bf16)v0.w;
      o[4] = (__bf16)v1.x; o[5] = (__bf16)v1.y;
      o[6] = (__bf16)v1.z; o[7] = (__bf16)v1.w;
      dst[h] = o;
    }
  } else {
    const size_t u = t - X_THREADS;            // 0 .. W_THREADS-1
    const size_t idx = u * 16;                 // flat (O,C) element index
    const int o_ = (int)(idx >> 12);           // / 4096
    const int grp = (int)(idx & 4095) >> 7;    // group of 128 (16 | 128)
    const float s = fmaxf(scales[(o_ << 5) + grp], 1e-8f);
    const float4* src = (const float4*)w + u * 4;
    bf16x8* dst = (bf16x8*)wb + u * 2;
#pragma unroll
    for (int h = 0; h < 2; ++h) {
      const float4 v0 = src[h * 2 + 0];
      const float4 v1 = src[h * 2 + 1];
      bf16x8 q;
      q[0] = (__bf16)((v0.x >= 0.f) ? s : -s);
      q[1] = (__bf16)((v0.y >= 0.f) ? s : -s);
      q[2] = (__bf16)((v0.z >= 0.f) ? s : -s);
      q[3] = (__bf16)((v0.w >= 0.f) ? s : -s);
      q[4] = (__bf16)((v1.x >= 0.f) ? s : -s);
      q[5] = (__bf16)((v1.y >= 0.f) ? s : -s);
      q[6] = (__bf16)((v1.z >= 0.f) ? s : -s);
      q[7] = (__bf16)((v1.w >= 0.f) ? s : -s);
      dst[h] = q;
    }
  }
}

// ---- GEMM ----
// LDS per buffer: A 256x32 bf16 (16 KiB) + B 256x32 bf16 (16 KiB), 4 buffers
// (128 KiB ring). Slot layout (slot = 16 B = 8 bf16 of k-chunk kc in 0..3):
//   slot(r, kc) = r*4 + (kc ^ ((r>>1)&3))   (SQ_LDS_BANK_CONFLICT == 0, R3/R4)
// Staging: lane l -> row l>>2 within 16-row slab, pre-swizzled global k-chunk
// kc = (l&3)^((l>>3)&3); LDS dest linear (uniform base + lane*16).
// 32x32x16 frag (R2-verified): A: m = lane&31, k = 8*(lane>>5)+j  ->
// read row = tile_row + (lane&31), kc = 2*ks + (lane>>5), ks in {0,1}.
// C/D: col = lane&31, row = (reg&3) + 8*(reg>>2) + 4*(lane>>5).
//
// Pipeline (k-step = 16): F0 = even-step frags, F1 = odd-step frags.
//   step 0: read F1 (this tile, ks=1)   | MFMA x8 consuming F0
//   step 1: read F0 (tile t+1, ks=0)    | MFMA x8 consuming F1
// Tile t stages tile t+3 (A in step 0, B in step 1). vmcnt(4) at tile end
// ensures DMA(t+1) landed before tile t+1... (see audit in comments below).

#define LDS_A(b) ((char*)lds + (b) * 32768)
#define LDS_B(b) ((char*)lds + (b) * 32768 + 16384)

#define STAGE_A_TO(b) do {                        \
    char* _d = LDS_A(b);                          \
    async_copy16(aP0, _d + dO0);                  \
    async_copy16(aP1, _d + dO1);                  \
  } while (0)

#define STAGE_B_TO(b) do {                        \
    char* _d = LDS_B(b);                          \
    async_copy16(bP0, _d + dO0);                  \
    async_copy16(bP1, _d + dO1);                  \
  } while (0)

#define ADVANCE do { aP0 += BK; aP1 += BK; bP0 += BK; bP1 += BK; } while (0)

// vmcnt audit (4 DMA/wave/tile; prologue stages tiles 0,1,2):
//   prologue: 12 outstanding, vmcnt(4) -> tiles 0,1 complete (tile 0 body
//     reads buf0 ks1 AND buf1 ks0).
//   end of tile t (staged t+3): outstanding t+1(4),t+2(4),t+3(4) minus done;
//     vmcnt(4) -> t+1 complete, needed by tile t+1's reads of buf[t+2]... and
//     its own buf[t+1] ks1 reads. WAW: DMA(t+3) overwrites buf[(t-1)&3]; all
//     reads of that buffer were consumed (lgkm) before barrier(end t-1). OK.
//   tail: end 124 -> vmcnt(4) (DMA 126 done); end 125 -> vmcnt(0) (DMA 127
//     done, read by tile 126 step 1); end 126 -> vmcnt(0) no-op.
#define TILE_BODY(BUF, DO_STAGE, DO_READN, VMSTR) do {                         \
    char* _bA = LDS_A(BUF);                                                    \
    char* _bB = LDS_B(BUF);                                                    \
    char* _nA = LDS_A((BUF + 1) & 3);                                          \
    char* _nB = LDS_B((BUF + 1) & 3);                                          \
    /* ---- step 0: read F1 (this tile ks=1); MFMA with F0 ---- */             \
    _Pragma("unroll") for (int _i = 0; _i < 4; ++_i)                           \
      F1a[_i] = *(const bf16x8*)(_bA + aOff[_i][1]);                           \
    _Pragma("unroll") for (int _j = 0; _j < 2; ++_j)                           \
      F1b[_j] = *(const bf16x8*)(_bB + bOff[_j][1]);                           \
    if (DO_STAGE) STAGE_A_TO((BUF + 3) & 3);                                   \
    __builtin_amdgcn_s_setprio(1);                                             \
    _Pragma("unroll") for (int _i = 0; _i < 4; ++_i)                           \
      _Pragma("unroll") for (int _j = 0; _j < 2; ++_j)                         \
        acc[_i][_j] = __builtin_amdgcn_mfma_f32_32x32x16_bf16(                 \
            F0a[_i], F0b[_j], acc[_i][_j], 0, 0, 0);                           \
    __builtin_amdgcn_s_setprio(0);                                             \
    /* ---- step 1: read F0 (next tile ks=0); MFMA with F1 ---- */             \
    if (DO_READN) {                                                            \
      _Pragma("unroll") for (int _i = 0; _i < 4; ++_i)                         \
        F0a[_i] = *(const bf16x8*)(_nA + aOff[_i][0]);                         \
      _Pragma("unroll") for (int _j = 0; _j < 2; ++_j)                         \
        F0b[_j] = *(const bf16x8*)(_nB + bOff[_j][0]);                         \
    }                                                                          \
    if (DO_STAGE) { STAGE_B_TO((BUF + 3) & 3); ADVANCE; }                      \
    __builtin_amdgcn_s_setprio(1);                                             \
    _Pragma("unroll") for (int _i = 0; _i < 4; ++_i)                           \
      _Pragma("unroll") for (int _j = 0; _j < 2; ++_j)                         \
        acc[_i][_j] = __builtin_amdgcn_mfma_f32_32x32x16_bf16(                 \
            F1a[_i], F1b[_j], acc[_i][_j], 0, 0, 0);                           \
    __builtin_amdgcn_s_setprio(0);                                             \
    asm volatile("s_waitcnt " VMSTR ::: "memory");                             \
    __builtin_amdgcn_s_barrier();                                              \
    __builtin_amdgcn_sched_barrier(0); /* tile boundary fence */               \
  } while (0)

__global__ __launch_bounds__(512, 2) void literati_gemm(
    const __bf16* __restrict__ Ab, const __bf16* __restrict__ Bb,
    float* __restrict__ C) {
  __shared__ __align__(16) char lds[4 * 32768];  // 128 KiB ring

  const int tid = threadIdx.x;
  const int lane = tid & 63;
  const int wave = tid >> 6;       // 0..7
  const int bn0 = blockIdx.x * BN;
  const int bm0 = blockIdx.y * BM;
  const int wm = wave >> 2;        // 0..1: 128-row half
  const int wn = wave & 3;         // 0..3: 64-col quarter

  // ---- staging decomposition (R4-verified) ----
  const int r_in = lane >> 2;                        // 0..15 row within slab
  const int kc_st = (lane & 3) ^ ((lane >> 3) & 3);  // pre-swizzled k-chunk
  const int c0 = wave * 2;                           // slab ids c0, c0+1
  const __bf16* aP0 = Ab + (size_t)(bm0 + c0 * 16 + r_in) * K_DIM + kc_st * 8;
  const __bf16* aP1 = Ab + (size_t)(bm0 + (c0 + 1) * 16 + r_in) * K_DIM + kc_st * 8;
  const __bf16* bP0 = Bb + (size_t)(bn0 + c0 * 16 + r_in) * K_DIM + kc_st * 8;
  const __bf16* bP1 = Bb + (size_t)(bn0 + (c0 + 1) * 16 + r_in) * K_DIM + kc_st * 8;
  const int dO0 = (c0 * 64 + lane) * 16;        // linear LDS byte offsets
  const int dO1 = ((c0 + 1) * 64 + lane) * 16;

  // ---- fragment LDS byte offsets (32x32x16) ----
  const int m32 = lane & 31;
  const int hl = lane >> 5;  // 0/1
  int aOff[4][2], bOff[2][2];
#pragma unroll
  for (int i = 0; i < 4; ++i) {
    const int row = wm * 128 + i * 32 + m32;
#pragma unroll
    for (int ks = 0; ks < 2; ++ks) {
      const int kc = 2 * ks + hl;
      aOff[i][ks] = (row * 4 + (kc ^ ((row >> 1) & 3))) * 16;
    }
  }
#pragma unroll
  for (int j = 0; j < 2; ++j) {
    const int row = wn * 64 + j * 32 + m32;
#pragma unroll
    for (int ks = 0; ks < 2; ++ks) {
      const int kc = 2 * ks + hl;
      bOff[j][ks] = (row * 4 + (kc ^ ((row >> 1) & 3))) * 16;
    }
  }

  f32x16 acc[4][2];
#pragma unroll
  for (int i = 0; i < 4; ++i)
#pragma unroll
    for (int j = 0; j < 2; ++j)
#pragma unroll
      for (int r = 0; r < 16; ++r) acc[i][j][r] = 0.f;

  bf16x8 F0a[4], F0b[2], F1a[4], F1b[2];

  // ---- prologue: stage tiles 0,1,2; wait tiles 0,1; load F0(tile0,ks0) ----
  STAGE_A_TO(0); STAGE_B_TO(0); ADVANCE;
  STAGE_A_TO(1); STAGE_B_TO(1); ADVANCE;
  STAGE_A_TO(2); STAGE_B_TO(2); ADVANCE;
  asm volatile("s_waitcnt vmcnt(4)" ::: "memory");
  __builtin_amdgcn_s_barrier();
  __builtin_amdgcn_sched_barrier(0);
#pragma unroll
  for (int i = 0; i < 4; ++i)
    F0a[i] = *(const bf16x8*)(LDS_A(0) + aOff[i][0]);
#pragma unroll
  for (int j = 0; j < 2; ++j)
    F0b[j] = *(const bf16x8*)(LDS_B(0) + bOff[j][0]);

  // ---- main loop: tiles 0..123, ring index compile-time ----
  for (int tq = 0; tq < 31; ++tq) {
    TILE_BODY(0, 1, 1, "vmcnt(4)");
    TILE_BODY(1, 1, 1, "vmcnt(4)");
    TILE_BODY(2, 1, 1, "vmcnt(4)");
    TILE_BODY(3, 1, 1, "vmcnt(4)");
  }
  // tile 124 stages tile 127; drain 125/126/127
  TILE_BODY(0, 1, 1, "vmcnt(4)");
  TILE_BODY(1, 0, 1, "vmcnt(0)");
  TILE_BODY(2, 0, 1, "vmcnt(0)");
  TILE_BODY(3, 0, 0, "vmcnt(0)");

  // ---- epilogue: col = lane&31, row = (r&3)+8*(r>>2)+4*hl (R2-verified) ----
#pragma unroll
  for (int i = 0; i < 4; ++i) {
#pragma unroll
    for (int j = 0; j < 2; ++j) {
      const int col = bn0 + wn * 64 + j * 32 + m32;
      const int rbase = bm0 + wm * 128 + i * 32 + 4 * hl;
#pragma unroll
      for (int r = 0; r < 16; ++r) {
        const int row = rbase + (r & 3) + 8 * (r >> 2);
        C[(size_t)row * N_DIM + col] = acc[i][j][r];
      }
    }
  }
}

extern "C" void kernel_launch(void* const* d_in, const int* in_sizes, int n_in,
                              void* d_out, int out_size, void* d_ws, size_t ws_size,
                              hipStream_t stream) {
  (void)in_sizes; (void)n_in; (void)out_size; (void)ws_size;
  const float* x = (const float*)d_in[0];      // (4,2048,4096) fp32
  const float* w = (const float*)d_in[1];      // (4096,4096) fp32
  const float* sc = (const float*)d_in[2];     // (4096,32) fp32
  float* out = (float*)d_out;                  // (4,2048,4096) fp32

  __bf16* xb = (__bf16*)d_ws;
  __bf16* wb = xb + (size_t)M_DIM * K_DIM;

  const size_t total_threads = X_THREADS + W_THREADS;  // 3M
  prep_kernel<<<(int)(total_threads / 256), 256, 0, stream>>>(x, w, sc, xb, wb);

  dim3 grid(N_DIM / BN, M_DIM / BM);  // (16, 32)
  literati_gemm<<<grid, 512, 0, stream>>>(xb, wb, out);
}